// Round 1
// baseline (568.334 us; speedup 1.0000x reference)
//
#include <hip/hip_runtime.h>

#define BB 32
#define SS 2048
#define DD 2048
#define KK 6

__global__ __launch_bounds__(256) void QueryTokenProbe_kernel(
    const float* __restrict__ hs,        // [B,S,D]
    const float* __restrict__ W,         // [K,D]
    const float* __restrict__ bias,      // [K]
    const int*   __restrict__ input_ids, // [B,S]
    const int*   __restrict__ attn,      // [B,S]
    const int*   __restrict__ token_ids, // [K]
    float*       __restrict__ out)       // [B,K]
{
    const int blk = blockIdx.x;          // 0 .. B*K-1
    const int b   = blk / KK;
    const int k   = blk - b * KK;
    const int tid = threadIdx.x;         // 0..255
    const int lane = tid & 63;
    const int wave = tid >> 6;

    const int tok = token_ids[k];

    // ---- Phase 1: scan ids/mask for last valid pos and last matching pos ----
    int local_valid = -1;
    int local_match = -1;
    const int4* ids4 = (const int4*)(input_ids + (size_t)b * SS);
    const int4* msk4 = (const int4*)(attn      + (size_t)b * SS);
    // S/4 = 512 int4 per row; 256 threads -> 2 each; positions ascend per thread
#pragma unroll
    for (int it = 0; it < 2; ++it) {
        const int idx  = tid + it * 256;
        const int4 id  = ids4[idx];
        const int4 m   = msk4[idx];
        const int base = idx * 4;
        if (m.x > 0) { local_valid = base + 0; if (id.x == tok) local_match = base + 0; }
        if (m.y > 0) { local_valid = base + 1; if (id.y == tok) local_match = base + 1; }
        if (m.z > 0) { local_valid = base + 2; if (id.z == tok) local_match = base + 2; }
        if (m.w > 0) { local_valid = base + 3; if (id.w == tok) local_match = base + 3; }
    }

    // wave64 max-reduce
#pragma unroll
    for (int off = 32; off > 0; off >>= 1) {
        local_valid = max(local_valid, __shfl_down(local_valid, off));
        local_match = max(local_match, __shfl_down(local_match, off));
    }
    __shared__ int s_valid[4];
    __shared__ int s_match[4];
    if (lane == 0) { s_valid[wave] = local_valid; s_match[wave] = local_match; }
    __syncthreads();
    const int last_valid = max(max(s_valid[0], s_valid[1]), max(s_valid[2], s_valid[3]));
    const int last_match = max(max(s_match[0], s_match[1]), max(s_match[2], s_match[3]));

    const bool has_valid = (last_valid >= 0);
    int final_pos = (last_match >= 0) ? last_match : last_valid;
    final_pos = min(max(final_pos, 0), SS - 1);   // clip

    // ---- Phase 2: dot(hs[b, final_pos, :], W[k, :]) ----
    const float4* h4 = (const float4*)(hs + ((size_t)b * SS + (size_t)final_pos) * DD);
    const float4* w4 = (const float4*)(W + (size_t)k * DD);
    float acc = 0.f;
#pragma unroll
    for (int it = 0; it < 2; ++it) {
        const int idx = tid + it * 256;   // D/4 = 512 float4
        const float4 h = h4[idx];
        const float4 w = w4[idx];
        acc += h.x * w.x + h.y * w.y + h.z * w.z + h.w * w.w;
    }
#pragma unroll
    for (int off = 32; off > 0; off >>= 1) acc += __shfl_down(acc, off);

    __shared__ float s_acc[4];
    if (lane == 0) s_acc[wave] = acc;
    __syncthreads();
    if (tid == 0) {
        const float total = s_acc[0] + s_acc[1] + s_acc[2] + s_acc[3];
        out[(size_t)b * KK + k] = has_valid ? (total + bias[k]) : 0.f;
    }
}

extern "C" void kernel_launch(void* const* d_in, const int* in_sizes, int n_in,
                              void* d_out, int out_size, void* d_ws, size_t ws_size,
                              hipStream_t stream) {
    const float* hs        = (const float*)d_in[0];
    const float* W         = (const float*)d_in[1];
    const float* bias      = (const float*)d_in[2];
    const int*   input_ids = (const int*)d_in[3];
    const int*   attn      = (const int*)d_in[4];
    const int*   token_ids = (const int*)d_in[5];
    float* out = (float*)d_out;

    QueryTokenProbe_kernel<<<BB * KK, 256, 0, stream>>>(
        hs, W, bias, input_ids, attn, token_ids, out);
}